// Round 7
// baseline (745.749 us; speedup 1.0000x reference)
//
#include <hip/hip_runtime.h>
#include <cstdint>
#include <cstddef>

// Problem constants (fixed by the reference)
#define NN   50000
#define MM   24
#define MH   12              // m-half per conv_partial phase
#define FNIN 92
#define FEIN 41
#define NBLK 3125            // NN / 16 nodes per conv block
#define EROW 48              // edge row padded 41 -> 48 bf16 (96 B)
#define ETILE (MM * 16 * EROW)  // 18432 elems per node-block tile

typedef __attribute__((ext_vector_type(8))) short bf16x8;
typedef __attribute__((ext_vector_type(4))) float f32x4;
typedef __attribute__((ext_vector_type(8))) unsigned short u16x8;
typedef __attribute__((ext_vector_type(2))) _Float16 f16x2;

__device__ __forceinline__ unsigned short f2bf(float x) {
    unsigned int u = __float_as_uint(x);
    return (unsigned short)((u + 0x7fffu + ((u >> 16) & 1u)) >> 16);  // RNE
}
__device__ __forceinline__ float bf2f(unsigned short h) {
    return __uint_as_float(((unsigned int)h) << 16);
}
__device__ __forceinline__ _Float16 f2h_clamp(float x) {
    return (_Float16)fminf(fmaxf(x, -60000.f), 60000.f);   // stay finite in fp16
}
__device__ __forceinline__ float softplusf(float x) {
    return fmaxf(x, 0.f) + __logf(1.0f + __expf(-fabsf(x)));
}

// P layout: fp16 pair-interleaved, P[node][2*c+0]=filter col c, [2*c+1]=core col c.
// Pn sentinel row at node==NN: filter=-60000 (sigmoid -> +0), core=0.

// ---------------------------------------------------------------------------
// prep: combined weights in MFMA B-fragment order + Pn sentinel. LDS-staged
// W/We so the 64-term dot products read LDS, not global.
// ---------------------------------------------------------------------------
__global__ __launch_bounds__(256) void prep_kernel(
    const float* __restrict__ We, const float* __restrict__ be,
    const float* __restrict__ W1, const float* __restrict__ b1,
    const float* __restrict__ W2, const float* __restrict__ b2,
    const float* __restrict__ W3, const float* __restrict__ b3,
    unsigned short* __restrict__ WcB,
    unsigned short* __restrict__ WsnBhi, unsigned short* __restrict__ WsnBlo,
    float* __restrict__ bias_c, _Float16* __restrict__ Pn)
{
    __shared__ float Wp[64 * 128];    // W[128+i][n]
    __shared__ float Wes[41 * 66];    // We[k][i] at stride 66 (bank-spread)
    int l = blockIdx.x / 24;
    int part = blockIdx.x % 24;
    const float* W  = (l == 0) ? W1 : (l == 1) ? W2 : W3;
    const float* bl = (l == 0) ? b1 : (l == 1) ? b2 : b3;
    int tid = threadIdx.x;
    if (blockIdx.x == 0 && tid < 128) {
        Pn[(size_t)NN * 128 + tid] = (tid & 1) ? (_Float16)0.f : (_Float16)(-60000.f);
    }
    if (part < 8) {
        int j = part;
        for (int i = tid; i < 64 * 128; i += 256) Wp[i] = W[(128 + (i >> 7)) * 128 + (i & 127)];
        for (int i = tid; i < FEIN * 64; i += 256) Wes[(i >> 6) * 66 + (i & 63)] = We[i];
        __syncthreads();
        for (int e = tid; e < 1024; e += 256) {
            int s = e >> 9, L = (e >> 3) & 63, t = e & 7;
            int k = s * 32 + ((L >> 4) << 3) + t;
            int n = 16 * j + (L & 15);
            float v = 0.f;
            if (k < FEIN) {
                #pragma unroll 8
                for (int i = 0; i < 64; ++i)
                    v += Wes[k * 66 + i] * Wp[i * 128 + n];
            }
            WcB[l * 8192 + j * 1024 + e] = f2bf(v);
        }
        if (part == 0 && tid < 128) {
            float v = bl[tid];
            for (int i = 0; i < 64; ++i)
                v += be[i] * Wp[i * 128 + tid];
            bias_c[l * 128 + tid] = v;
        }
    } else {
        int j = part - 8;
        for (int e = tid; e < 1024; e += 256) {
            int s = e >> 9, L = (e >> 3) & 63, t = e & 7;
            int k = s * 32 + ((L >> 4) << 3) + t;
            int n = 16 * j + (L & 15);
            float v = (n < 128) ? W[k * 128 + n] : W[(64 + k) * 128 + (n - 128)];
            unsigned short h = f2bf(v);
            WsnBhi[l * 16384 + j * 1024 + e] = h;
            WsnBlo[l * 16384 + j * 1024 + e] = f2bf(v - bf2f(h));
        }
    }
}

// ---------------------------------------------------------------------------
// cast: edge_fea (N,M,41) fp32 -> block-tiled bf16, m-major rows, k pad to 48.
// ---------------------------------------------------------------------------
#define CN 8
__global__ __launch_bounds__(256) void cast_kernel(
    const float* __restrict__ edge_fea, unsigned short* __restrict__ edge_tiles)
{
    __shared__ float s[CN * MM * FEIN];
    int B = blockIdx.x;
    int b = B >> 1, half = B & 1;
    const float4* src = (const float4*)(edge_fea + ((size_t)b * 16 + half * CN) * (MM * FEIN));
    float4* sd = (float4*)s;
    for (int i = threadIdx.x; i < (CN * MM * FEIN) / 4; i += 256)
        sd[i] = src[i];
    __syncthreads();
    unsigned short* dst = edge_tiles + (size_t)b * ETILE;
    for (int c = threadIdx.x; c < CN * MM * 6; c += 256) {
        int r = c / 6, cc = c - r * 6;
        int m = r >> 3, nbl = r & 7;
        int k0 = cc * 8;
        const float* srow = &s[(nbl * MM + m) * FEIN];
        u16x8 v;
        #pragma unroll
        for (int j = 0; j < 8; ++j) {
            int k = k0 + j;
            v[j] = (k < FEIN) ? f2bf(srow[k]) : (unsigned short)0;
        }
        *(u16x8*)(dst + (size_t)(m * 16 + half * CN + nbl) * EROW + k0) = v;
    }
}

// ---------------------------------------------------------------------------
// embed: node0 = node_fea @ Wn + bn. 32 nodes/block (2x wave count vs 64).
// ---------------------------------------------------------------------------
__global__ __launch_bounds__(256) void embed_kernel(
    const float* __restrict__ node_fea, const float* __restrict__ Wn,
    const float* __restrict__ bn, float* __restrict__ node_out)
{
    __shared__ float w_s[FNIN * 64];
    __shared__ float f_s[32 * FNIN];
    int tid = threadIdx.x;
    int base = blockIdx.x * 32;
    int cnt = min(32, NN - base);
    for (int i = tid; i < FNIN * 64; i += 256) w_s[i] = Wn[i];
    for (int i = tid; i < cnt * FNIN; i += 256) f_s[i] = node_fea[base * FNIN + i];
    __syncthreads();
    int c = tid & 63, g = tid >> 6;
    float acc[8];
    #pragma unroll
    for (int jj = 0; jj < 8; ++jj) acc[jj] = 0.f;
    for (int k = 0; k < FNIN; ++k) {
        float wv = w_s[k * 64 + c];
        #pragma unroll
        for (int jj = 0; jj < 8; ++jj)
            acc[jj] += f_s[(g + 4 * jj) * FNIN + k] * wv;
    }
    float bv = bn[c];
    #pragma unroll
    for (int jj = 0; jj < 8; ++jj) {
        int n = g + 4 * jj;
        if (n < cnt) node_out[(base + n) * 64 + c] = acc[jj] + bv;
    }
}

// ---------------------------------------------------------------------------
// p_fused: (optionally) finalize the previous conv layer, then compute the
// P tables for the next: node = softplus(alpha*prev + accA + accB) (flag!=0),
// Ps/Pn = node @ [W_s | W_n] via split-bf16 MFMA, fp16 pair-interleaved.
// gridDim = (782, 4): blockIdx.y owns 2 jp pairs (y<2 -> Ps, y>=2 -> Pn).
// y==0 also writes the finalized node to global (needed by the next finalize).
// ---------------------------------------------------------------------------
__global__ __launch_bounds__(256) void p_fused_kernel(
    const float* __restrict__ node_prev,
    const float* __restrict__ accA, const float* __restrict__ accB,
    const float* __restrict__ alpha_p, int useacc,
    const unsigned short* __restrict__ Bhi, const unsigned short* __restrict__ Blo,
    _Float16* __restrict__ Ps, _Float16* __restrict__ Pn,
    float* __restrict__ node_out)
{
    __shared__ float n_s[64 * 68];
    int tid = threadIdx.x;
    int base = blockIdx.x * 64;
    int cnt = min(64, NN - base);
    float alpha = useacc ? alpha_p[0] : 0.f;
    for (int i = tid; i < cnt * 64; i += 256) {
        int r = i >> 6, c = i & 63;
        float x = node_prev[base * 64 + i];
        if (useacc) {
            x = softplusf(alpha * x + accA[base * 64 + i] + accB[base * 64 + i]);
            if (blockIdx.y == 0) node_out[base * 64 + i] = x;
        }
        n_s[r * 68 + c] = x;
    }
    __syncthreads();
    int w = tid >> 6, L = tid & 63, quad = L >> 4, lc = L & 15;
    const float* ap = &n_s[(16 * w + lc) * 68 + quad * 8];
    bf16x8 a0h, a0l, a1h, a1l;
    for (int t = 0; t < 8; ++t) {
        float x0 = ap[t];
        float x1 = ap[32 + t];
        unsigned short h0 = f2bf(x0), h1 = f2bf(x1);
        a0h[t] = (short)h0; a1h[t] = (short)h1;
        a0l[t] = (short)f2bf(x0 - bf2f(h0));
        a1l[t] = (short)f2bf(x1 - bf2f(h1));
    }
    const bf16x8* bh = (const bf16x8*)Bhi;
    const bf16x8* bl = (const bf16x8*)Blo;
    int jp0 = blockIdx.y * 2;
    #pragma unroll
    for (int q = 0; q < 2; ++q) {
        int jp = jp0 + q;
        int jf = (jp < 4) ? jp : (jp + 4);       // filter tile
        int jc = jf + 4;                         // core tile
        bf16x8 f0h = bh[(jf * 2 + 0) * 64 + L];
        bf16x8 f1h = bh[(jf * 2 + 1) * 64 + L];
        bf16x8 f0l = bl[(jf * 2 + 0) * 64 + L];
        bf16x8 f1l = bl[(jf * 2 + 1) * 64 + L];
        bf16x8 c0h = bh[(jc * 2 + 0) * 64 + L];
        bf16x8 c1h = bh[(jc * 2 + 1) * 64 + L];
        bf16x8 c0l = bl[(jc * 2 + 0) * 64 + L];
        bf16x8 c1l = bl[(jc * 2 + 1) * 64 + L];
        f32x4 Cf = {0.f, 0.f, 0.f, 0.f}, Cc = {0.f, 0.f, 0.f, 0.f};
        Cf = __builtin_amdgcn_mfma_f32_16x16x32_bf16(a0h, f0h, Cf, 0, 0, 0);
        Cf = __builtin_amdgcn_mfma_f32_16x16x32_bf16(a1h, f1h, Cf, 0, 0, 0);
        Cf = __builtin_amdgcn_mfma_f32_16x16x32_bf16(a0l, f0h, Cf, 0, 0, 0);
        Cf = __builtin_amdgcn_mfma_f32_16x16x32_bf16(a1l, f1h, Cf, 0, 0, 0);
        Cf = __builtin_amdgcn_mfma_f32_16x16x32_bf16(a0h, f0l, Cf, 0, 0, 0);
        Cf = __builtin_amdgcn_mfma_f32_16x16x32_bf16(a1h, f1l, Cf, 0, 0, 0);
        Cc = __builtin_amdgcn_mfma_f32_16x16x32_bf16(a0h, c0h, Cc, 0, 0, 0);
        Cc = __builtin_amdgcn_mfma_f32_16x16x32_bf16(a1h, c1h, Cc, 0, 0, 0);
        Cc = __builtin_amdgcn_mfma_f32_16x16x32_bf16(a0l, c0h, Cc, 0, 0, 0);
        Cc = __builtin_amdgcn_mfma_f32_16x16x32_bf16(a1l, c1h, Cc, 0, 0, 0);
        Cc = __builtin_amdgcn_mfma_f32_16x16x32_bf16(a0h, c0l, Cc, 0, 0, 0);
        Cc = __builtin_amdgcn_mfma_f32_16x16x32_bf16(a1h, c1l, Cc, 0, 0, 0);
        int cl = (jp < 4) ? (16 * jp + lc) : (16 * (jp - 4) + lc);   // col in [0,64)
        _Float16* P = (jp < 4) ? Ps : Pn;
        #pragma unroll
        for (int r = 0; r < 4; ++r) {
            int nr = 16 * w + quad * 4 + r;
            if (nr < cnt) {
                f16x2 v = {f2h_clamp(Cf[r]), f2h_clamp(Cc[r])};
                *(f16x2*)&P[(size_t)(base + nr) * 128 + 2 * cl] = v;
            }
        }
    }
}

// ---------------------------------------------------------------------------
// conv_partial: gridDim=(NBLK, 2). Phase y handles m in [12y, 12y+12) and
// writes its partial neighbor-sum (16 nodes x 64 cols) to its own buffer.
// Rolling depth-1 prefetch; sentinel row in Pn kills all mask ops.
// ---------------------------------------------------------------------------
__global__ __launch_bounds__(256) void conv_partial_kernel(
    const int* __restrict__ idx,
    const unsigned short* __restrict__ edge_tiles,
    const _Float16* __restrict__ Ps, const _Float16* __restrict__ Pn,
    const unsigned short* __restrict__ WcB, const float* __restrict__ bias_c,
    float* __restrict__ accA, float* __restrict__ accB)
{
    __shared__ unsigned ofs_s[16 * 13];     // (gg<<8) per (node, local m); stride 13
    int tid = threadIdx.x;
    int b = blockIdx.x;
    int ph = blockIdx.y;
    int m0 = ph * MH;
    int base = b * 16;
    for (int i = tid; i < 16 * MH; i += 256) {   // 192 elems, one pass
        int row = i / MH, m = i - row * MH;
        int g = idx[(base + row) * MM + m0 + m];
        unsigned gg = (unsigned)((g >= 0) ? g : NN);   // NN = sentinel row
        ofs_s[row * 13 + m] = gg << 8;                 // byte offset of Pn row
    }
    __syncthreads();

    int w = tid >> 6, L = tid & 63, quad = L >> 4, lc = L & 15;
    int colf = 16 * w + lc;
    const bf16x8* wcb = (const bf16x8*)WcB;
    bf16x8 bf0 = wcb[(w * 2 + 0) * 64 + L];
    bf16x8 bf1 = wcb[(w * 2 + 1) * 64 + L];
    bf16x8 bc0 = wcb[((w + 4) * 2 + 0) * 64 + L];
    bf16x8 bc1 = wcb[((w + 4) * 2 + 1) * 64 + L];

    float bias_f = bias_c[colf];
    float bias_g = bias_c[64 + colf];
    float psb_f[4], psb_c[4];
    #pragma unroll
    for (int r = 0; r < 4; ++r) {
        int nr = base + quad * 4 + r;
        f16x2 sp = *(const f16x2*)&Ps[(size_t)nr * 128 + 2 * colf];
        psb_f[r] = (float)sp[0] + bias_f;
        psb_c[r] = (float)sp[1] + bias_g;
    }

    float acc[4] = {0.f, 0.f, 0.f, 0.f};
    const char* PnB = (const char*)Pn;
    unsigned coff = (unsigned)colf << 2;
    const unsigned* ofsr = &ofs_s[quad * 4 * 13];
    const unsigned short* et = edge_tiles + (size_t)b * ETILE
                               + (size_t)m0 * (16 * EROW) + lc * EROW + quad * 8;

    // ---- prefetch local m=0 ----
    f16x2 pn[4];
    #pragma unroll
    for (int r = 0; r < 4; ++r)
        pn[r] = *(const f16x2*)(PnB + (ofsr[r * 13] + coff));
    bf16x8 a0 = *(const bf16x8*)(et);
    bf16x8 a1 = *(const bf16x8*)(et + 32);

    for (int m = 0; m < MH - 1; ++m) {
        f16x2 pn2[4];
        #pragma unroll
        for (int r = 0; r < 4; ++r)
            pn2[r] = *(const f16x2*)(PnB + (ofsr[r * 13 + (m + 1)] + coff));
        const unsigned short* etn = et + (m + 1) * (16 * EROW);
        bf16x8 na0 = *(const bf16x8*)(etn);
        bf16x8 na1 = *(const bf16x8*)(etn + 32);
        f32x4 Cf = {0.f, 0.f, 0.f, 0.f}, Cc = {0.f, 0.f, 0.f, 0.f};
        Cf = __builtin_amdgcn_mfma_f32_16x16x32_bf16(a0, bf0, Cf, 0, 0, 0);
        Cf = __builtin_amdgcn_mfma_f32_16x16x32_bf16(a1, bf1, Cf, 0, 0, 0);
        Cc = __builtin_amdgcn_mfma_f32_16x16x32_bf16(a0, bc0, Cc, 0, 0, 0);
        Cc = __builtin_amdgcn_mfma_f32_16x16x32_bf16(a1, bc1, Cc, 0, 0, 0);
        #pragma unroll
        for (int r = 0; r < 4; ++r) {
            float gf = Cf[r] + psb_f[r] + (float)pn[r][0];
            float gc = Cc[r] + psb_c[r] + (float)pn[r][1];
            float sg = 1.0f / (1.0f + __expf(-gf));   // sentinel: 1/(1+inf) = +0
            float sp = softplusf(gc);
            acc[r] += sg * sp;
        }
        #pragma unroll
        for (int r = 0; r < 4; ++r) pn[r] = pn2[r];
        a0 = na0; a1 = na1;
    }
    {   // epilogue: local m = MH-1
        f32x4 Cf = {0.f, 0.f, 0.f, 0.f}, Cc = {0.f, 0.f, 0.f, 0.f};
        Cf = __builtin_amdgcn_mfma_f32_16x16x32_bf16(a0, bf0, Cf, 0, 0, 0);
        Cf = __builtin_amdgcn_mfma_f32_16x16x32_bf16(a1, bf1, Cf, 0, 0, 0);
        Cc = __builtin_amdgcn_mfma_f32_16x16x32_bf16(a0, bc0, Cc, 0, 0, 0);
        Cc = __builtin_amdgcn_mfma_f32_16x16x32_bf16(a1, bc1, Cc, 0, 0, 0);
        #pragma unroll
        for (int r = 0; r < 4; ++r) {
            float gf = Cf[r] + psb_f[r] + (float)pn[r][0];
            float gc = Cc[r] + psb_c[r] + (float)pn[r][1];
            float sg = 1.0f / (1.0f + __expf(-gf));
            float sp = softplusf(gc);
            acc[r] += sg * sp;
        }
    }
    float* accbuf = ph ? accB : accA;
    #pragma unroll
    for (int r = 0; r < 4; ++r) {
        int nr = base + quad * 4 + r;
        accbuf[nr * 64 + colf] = acc[r];
    }
}

// ---------------------------------------------------------------------------
// finalize3: out = softplus(alpha*node + accA + accB), float4-vectorized.
// ---------------------------------------------------------------------------
__global__ __launch_bounds__(256) void finalize3_kernel(
    const float* __restrict__ node, const float* __restrict__ accA,
    const float* __restrict__ accB, const float* __restrict__ alpha_p,
    float* __restrict__ out)
{
    int i = blockIdx.x * 256 + threadIdx.x;   // 800000 float4 = 3125 blocks
    float alpha = alpha_p[0];
    float4 x = ((const float4*)node)[i];
    float4 a = ((const float4*)accA)[i];
    float4 b = ((const float4*)accB)[i];
    float4 o;
    o.x = softplusf(alpha * x.x + a.x + b.x);
    o.y = softplusf(alpha * x.y + a.y + b.y);
    o.z = softplusf(alpha * x.z + a.z + b.z);
    o.w = softplusf(alpha * x.w + a.w + b.w);
    ((float4*)out)[i] = o;
}

// ---------------------------------------------------------------------------
extern "C" void kernel_launch(void* const* d_in, const int* in_sizes, int n_in,
                              void* d_out, int out_size, void* d_ws, size_t ws_size,
                              hipStream_t stream)
{
    const float* node_fea = (const float*)d_in[0];
    const float* edge_fea = (const float*)d_in[1];
    const int*   eidx     = (const int*)d_in[2];
    const float* Wn = (const float*)d_in[3];
    const float* bn = (const float*)d_in[4];
    const float* We = (const float*)d_in[5];
    const float* be = (const float*)d_in[6];
    const float* W1 = (const float*)d_in[7];
    const float* b1 = (const float*)d_in[8];
    const float* a1 = (const float*)d_in[9];
    const float* W2 = (const float*)d_in[10];
    const float* b2 = (const float*)d_in[11];
    const float* a2 = (const float*)d_in[12];
    const float* W3 = (const float*)d_in[13];
    const float* b3 = (const float*)d_in[14];
    const float* a3 = (const float*)d_in[15];
    float* out = (float*)d_out;

    // Workspace layout (~192.3 MiB total; nodeE reused as node2)
    char* ws = (char*)d_ws;
    unsigned short* edge_tiles = (unsigned short*)ws;   // 115,200,000 B + 256 pad
    size_t off = 115200256;
    float* nodeE  = (float*)(ws + off); off += 12800000;   // embed out; later node2
    float* node1  = (float*)(ws + off); off += 12800000;
    float* accA   = (float*)(ws + off); off += 12800000;
    float* accB   = (float*)(ws + off); off += 12800000;
    _Float16* Ps  = (_Float16*)(ws + off); off += 12800000;
    _Float16* Pn  = (_Float16*)(ws + off); off += 12800256;   // +256 B sentinel row
    unsigned short* WcB    = (unsigned short*)(ws + off); off += 3 * 8192 * 2;
    unsigned short* WsnBhi = (unsigned short*)(ws + off); off += 3 * 16384 * 2;
    unsigned short* WsnBlo = (unsigned short*)(ws + off); off += 3 * 16384 * 2;
    float* bias_c = (float*)(ws + off); off += 3 * 128 * 4;
    float* node2 = nodeE;   // reuse: nodeE fully consumed before node2 is written

    prep_kernel<<<dim3(72), dim3(256), 0, stream>>>(We, be, W1, b1, W2, b2, W3, b3,
                                                    WcB, WsnBhi, WsnBlo, bias_c, Pn);
    cast_kernel<<<dim3(2 * NBLK), dim3(256), 0, stream>>>(edge_fea, edge_tiles);
    embed_kernel<<<dim3(1563), dim3(256), 0, stream>>>(node_fea, Wn, bn, nodeE);

    // layer 1
    p_fused_kernel<<<dim3(782, 4), dim3(256), 0, stream>>>(
        nodeE, accA, accB, a1, 0, WsnBhi, WsnBlo, Ps, Pn, node1 /*unused*/);
    conv_partial_kernel<<<dim3(NBLK, 2), dim3(256), 0, stream>>>(
        eidx, edge_tiles, Ps, Pn, WcB, bias_c, accA, accB);

    // layer 2 (finalizes layer 1 inside p_fused)
    p_fused_kernel<<<dim3(782, 4), dim3(256), 0, stream>>>(
        nodeE, accA, accB, a1, 1, WsnBhi + 16384, WsnBlo + 16384, Ps, Pn, node1);
    conv_partial_kernel<<<dim3(NBLK, 2), dim3(256), 0, stream>>>(
        eidx, edge_tiles, Ps, Pn, WcB + 8192, bias_c + 128, accA, accB);

    // layer 3 (finalizes layer 2 inside p_fused)
    p_fused_kernel<<<dim3(782, 4), dim3(256), 0, stream>>>(
        node1, accA, accB, a2, 1, WsnBhi + 32768, WsnBlo + 32768, Ps, Pn, node2);
    conv_partial_kernel<<<dim3(NBLK, 2), dim3(256), 0, stream>>>(
        eidx, edge_tiles, Ps, Pn, WcB + 16384, bias_c + 256, accA, accB);

    finalize3_kernel<<<dim3(3125), dim3(256), 0, stream>>>(node2, accA, accB, a3, out);
}